// Round 2
// baseline (188.476 us; speedup 1.0000x reference)
//
#include <hip/hip_runtime.h>

#define E_ 56
#define DIM_ 512
#define V_ 256
#define F_ 504       // E_*9
#define NROWS 65536  // B*L

__device__ __forceinline__ float sigmoidf_(float v) { return 1.0f / (1.0f + expf(-v)); }
__device__ __forceinline__ float bf2f_(unsigned short u) {
  return __uint_as_float(((unsigned int)u) << 16);
}
__device__ __forceinline__ unsigned short f2bf_(float f) {  // round-nearest-even
  unsigned int b = __float_as_uint(f);
  b += 0x7FFFu + ((b >> 16) & 1u);
  return (unsigned short)(b >> 16);
}

// ---------------- Weff fold: conv + gate + projection -> one linear map ----
// Wt layout: [q][c][d], d contiguous. BF selects bf16 vs f32 storage.
template<bool BF>
__global__ __launch_bounds__(256) void k_weff(
    const float* __restrict__ proj_w,   // [512][504]
    const float* __restrict__ conv_w,   // [56][56][3][3]
    const float* __restrict__ alpha,    // [9]
    void* __restrict__ Wt)
{
  int idx = blockIdx.x * 256 + threadIdx.x;   // 512*504 threads
  int d = idx / F_;
  int f = idx - d * F_;
  int c = f / 9;
  int q = f - c * 9;
  int qi = q / 3, qj = q - qi * 3;
  const float* pr = proj_w + d * F_;
  float acc = sigmoidf_(alpha[q]) * pr[c * 9 + q];
  for (int pi = 0; pi < 3; ++pi) {
    for (int pj = 0; pj < 3; ++pj) {
      int ki = qi - pi + 1, kj = qj - pj + 1;
      if (ki < 0 || ki > 2 || kj < 0 || kj > 2) continue;
      int p = pi * 3 + pj;
      const float* cwp = conv_w + c * 9 + (ki * 3 + kj);
      const float* prp = pr + p;
      float s = 0.f;
      #pragma unroll 8
      for (int e = 0; e < E_; ++e)
        s += prp[e * 9] * cwp[e * F_];
      acc += (1.f - sigmoidf_(alpha[p])) * s;
    }
  }
  size_t o = (size_t)(q * E_ + c) * DIM_ + d;
  if (BF) ((unsigned short*)Wt)[o] = f2bf_(acc);
  else    ((float*)Wt)[o] = acc;
}

__global__ __launch_bounds__(256) void k_beff(
    const float* __restrict__ proj_w,
    const float* __restrict__ conv_b,
    const float* __restrict__ proj_b,
    const float* __restrict__ alpha,
    float* __restrict__ beff)           // [512]
{
  int d = blockIdx.x * 256 + threadIdx.x;
  if (d >= DIM_) return;
  const float* pr = proj_w + d * F_;
  float acc = proj_b[d];
  for (int p = 0; p < 9; ++p) {
    float s = 0.f;
    for (int e = 0; e < E_; ++e) s += pr[e * 9 + p] * conv_b[e];
    acc += (1.f - sigmoidf_(alpha[p])) * s;
  }
  beff[d] = acc;
}

// T[q][t][d] = sum_c emb[t][c] * Wt[q][c][d]
template<bool WBF, bool TBF>
__global__ __launch_bounds__(256) void k_tab(
    const float* __restrict__ emb,      // [256][56]
    const void*  __restrict__ Wt,       // [9][56][512]
    void*        __restrict__ T)        // [9][256][512]
{
  int q = blockIdx.x >> 8;
  int t = blockIdx.x & 255;
  int d0 = 2 * threadIdx.x;
  const float* er = emb + t * E_;
  float a0 = 0.f, a1 = 0.f;
  for (int c = 0; c < E_; ++c) {
    float ev = er[c];
    float w0, w1;
    size_t wo = (size_t)(q * E_ + c) * DIM_ + d0;
    if (WBF) {
      unsigned int u = *(const unsigned int*)((const unsigned short*)Wt + wo);
      w0 = __uint_as_float(u << 16);
      w1 = __uint_as_float(u & 0xFFFF0000u);
    } else {
      float2 v = *(const float2*)((const float*)Wt + wo);
      w0 = v.x; w1 = v.y;
    }
    a0 += ev * w0; a1 += ev * w1;
  }
  size_t o = (size_t)(q * V_ + t) * DIM_ + d0;
  if (TBF) {
    unsigned int u = (unsigned int)f2bf_(a0) | ((unsigned int)f2bf_(a1) << 16);
    *(unsigned int*)((unsigned short*)T + o) = u;
  } else {
    *(float2*)((float*)T + o) = make_float2(a0, a1);
  }
}

// Shared LayerNorm tail: one wave owns one row held as 2x float4 per lane.
__device__ __forceinline__ void ln_write(float4 a0, float4 a1, int lane,
    const float* __restrict__ gamma, const float* __restrict__ beta,
    float4* __restrict__ o4)
{
  float s  = a0.x + a0.y + a0.z + a0.w + a1.x + a1.y + a1.z + a1.w;
  float ss = a0.x*a0.x + a0.y*a0.y + a0.z*a0.z + a0.w*a0.w
           + a1.x*a1.x + a1.y*a1.y + a1.z*a1.z + a1.w*a1.w;
  #pragma unroll
  for (int off = 32; off > 0; off >>= 1) {
    s  += __shfl_xor(s, off, 64);
    ss += __shfl_xor(ss, off, 64);
  }
  float mu   = s * (1.0f / 512.0f);
  float var  = ss * (1.0f / 512.0f) - mu * mu;
  float rstd = rsqrtf(var + 1e-5f);
  const float4* g4  = (const float4*)gamma;
  const float4* be4 = (const float4*)beta;
  float4 G0 = g4[lane], G1 = g4[64 + lane];
  float4 B0 = be4[lane], B1 = be4[64 + lane];
  float4 o0, o1;
  o0.x = (a0.x - mu) * rstd * G0.x + B0.x;
  o0.y = (a0.y - mu) * rstd * G0.y + B0.y;
  o0.z = (a0.z - mu) * rstd * G0.z + B0.z;
  o0.w = (a0.w - mu) * rstd * G0.w + B0.w;
  o1.x = (a1.x - mu) * rstd * G1.x + B1.x;
  o1.y = (a1.y - mu) * rstd * G1.y + B1.y;
  o1.z = (a1.z - mu) * rstd * G1.z + B1.z;
  o1.w = (a1.w - mu) * rstd * G1.w + B1.w;
  o4[lane] = o0;
  o4[64 + lane] = o1;
}

// One wave per row: 9 table gathers + LayerNorm.
template<bool TBF>
__global__ __launch_bounds__(256) void k_main(
    const int*   __restrict__ x,        // [65536][9]
    const void*  __restrict__ T,        // [9][256][512]
    const float* __restrict__ beff,
    const float* __restrict__ gamma,
    const float* __restrict__ beta,
    float* __restrict__ out)            // [65536][512]
{
  int gid = blockIdx.x * 256 + threadIdx.x;
  int row = gid >> 6;
  int lane = threadIdx.x & 63;
  int tok = 0;
  if (lane < 9) tok = x[row * 9 + lane];

  const float4* b4 = (const float4*)beff;
  float4 a0 = b4[lane];
  float4 a1 = b4[64 + lane];

  #pragma unroll
  for (int q = 0; q < 9; ++q) {
    int t = __shfl(tok, q, 64);
    size_t base = (size_t)((q << 8) + t) * DIM_;
    if (TBF) {
      const ushort4* p0 = (const ushort4*)((const unsigned short*)T + base);
      ushort4 u0 = p0[lane];
      ushort4 u1 = p0[64 + lane];
      a0.x += bf2f_(u0.x); a0.y += bf2f_(u0.y); a0.z += bf2f_(u0.z); a0.w += bf2f_(u0.w);
      a1.x += bf2f_(u1.x); a1.y += bf2f_(u1.y); a1.z += bf2f_(u1.z); a1.w += bf2f_(u1.w);
    } else {
      const float4* p0 = (const float4*)((const float*)T + base);
      float4 v0 = p0[lane];
      float4 v1 = p0[64 + lane];
      a0.x += v0.x; a0.y += v0.y; a0.z += v0.z; a0.w += v0.w;
      a1.x += v1.x; a1.y += v1.y; a1.z += v1.z; a1.w += v1.w;
    }
  }
  ln_write(a0, a1, lane, gamma, beta, (float4*)(out + (size_t)row * DIM_));
}

// ----------------- D bracket (tiny ws): no T table -------------------------
__global__ __launch_bounds__(256) void k_init(
    const float* __restrict__ beff, float* __restrict__ out)
{
  int idx = blockIdx.x * 256 + threadIdx.x;     // 8,388,608 float4s
  ((float4*)out)[idx] = ((const float4*)beff)[idx & 127];
}

// out[row][d] += sum_c emb[x[row][q]][c] * Weff[q][c][d]   (one q per launch)
__global__ __launch_bounds__(256) void k_accq(
    const int* __restrict__ x,
    const float* __restrict__ emb,
    const unsigned short* __restrict__ Wt,      // bf16 [9][56][512]
    float* __restrict__ out, int q)
{
  const int tid = threadIdx.x;
  const int d = blockIdx.y * 256 + tid;
  const int row0 = blockIdx.x * 512;
  const unsigned short* wq = Wt + (size_t)(q * E_) * DIM_ + d;

  for (int rb = 0; rb < 512; rb += 8) {
    int tv[8]; float a[8];
    #pragma unroll
    for (int j = 0; j < 8; ++j) {
      tv[j] = x[(size_t)(row0 + rb + j) * 9 + q];
      a[j] = 0.f;
    }
    for (int c = 0; c < E_; ++c) {
      float w = bf2f_(wq[(size_t)c * DIM_]);
      #pragma unroll
      for (int j = 0; j < 8; ++j)
        a[j] += emb[tv[j] * E_ + c] * w;
    }
    #pragma unroll
    for (int j = 0; j < 8; ++j) {
      size_t o = (size_t)(row0 + rb + j) * DIM_ + d;
      out[o] += a[j];
    }
  }
}

__global__ __launch_bounds__(256) void k_ln(
    const float* __restrict__ gamma, const float* __restrict__ beta,
    float* __restrict__ out)
{
  int gid = blockIdx.x * 256 + threadIdx.x;
  int row = gid >> 6;
  int lane = threadIdx.x & 63;
  float4* o4 = (float4*)(out + (size_t)row * DIM_);
  float4 a0 = o4[lane];
  float4 a1 = o4[64 + lane];
  ln_write(a0, a1, lane, gamma, beta, o4);
}

extern "C" void kernel_launch(void* const* d_in, const int* in_sizes, int n_in,
                              void* d_out, int out_size, void* d_ws, size_t ws_size,
                              hipStream_t stream) {
  const int*   x      = (const int*)  d_in[0];
  const float* emb    = (const float*)d_in[1];
  const float* alpha  = (const float*)d_in[2];
  const float* conv_w = (const float*)d_in[3];
  const float* conv_b = (const float*)d_in[4];
  const float* proj_w = (const float*)d_in[5];
  const float* proj_b = (const float*)d_in[6];
  const float* gamma  = (const float*)d_in[7];
  const float* beta   = (const float*)d_in[8];
  float* out = (float*)d_out;

  // ws layout: beff f32 @0 (2048 B); then Wt; then T.
  float* beff = (float*)d_ws;
  char* wsbase = (char*)d_ws;

  const size_t WT_F32 = (size_t)9 * E_ * DIM_ * 4;   // 1,032,192
  const size_t WT_BF  = (size_t)9 * E_ * DIM_ * 2;   //   516,096
  const size_t T_F32  = (size_t)9 * V_ * DIM_ * 4;   // 4,718,592
  const size_t T_BF   = (size_t)9 * V_ * DIM_ * 2;   // 2,359,296

  const size_t needAfull = 2048 + WT_F32 + T_F32;    // 5,752,832
  const size_t needA3    = 2048 + WT_BF  + T_F32;    // 5,236,736
  const size_t needB3    = 2048 + WT_BF  + T_BF;     // 2,877,440

  hipLaunchKernelGGL(k_beff, dim3(2), dim3(256), 0, stream,
                     proj_w, conv_b, proj_b, alpha, beff);

  if (ws_size >= needAfull) {
    // A_full: all-f32 (round-1 math; only triggers if ws is large)
    float* Wt = (float*)(wsbase + 2048);
    float* T  = (float*)(wsbase + 2048 + WT_F32);
    hipLaunchKernelGGL((k_weff<false>), dim3((DIM_ * F_) / 256), dim3(256), 0, stream,
                       proj_w, conv_w, alpha, (void*)Wt);
    hipLaunchKernelGGL((k_tab<false, false>), dim3(9 * V_), dim3(256), 0, stream,
                       emb, (const void*)Wt, (void*)T);
    hipLaunchKernelGGL((k_main<false>), dim3(NROWS / 4), dim3(256), 0, stream,
                       x, (const void*)T, beff, gamma, beta, out);
  } else if (ws_size >= needA3) {
    // A3: Wt bf16 + T f32
    unsigned short* Wt = (unsigned short*)(wsbase + 2048);
    float* T = (float*)(wsbase + 2048 + WT_BF);
    hipLaunchKernelGGL((k_weff<true>), dim3((DIM_ * F_) / 256), dim3(256), 0, stream,
                       proj_w, conv_w, alpha, (void*)Wt);
    hipLaunchKernelGGL((k_tab<true, false>), dim3(9 * V_), dim3(256), 0, stream,
                       emb, (const void*)Wt, (void*)T);
    hipLaunchKernelGGL((k_main<false>), dim3(NROWS / 4), dim3(256), 0, stream,
                       x, (const void*)T, beff, gamma, beta, out);
  } else if (ws_size >= needB3) {
    // B3: Wt bf16 + T bf16
    unsigned short* Wt = (unsigned short*)(wsbase + 2048);
    unsigned short* T = (unsigned short*)(wsbase + 2048 + WT_BF);
    hipLaunchKernelGGL((k_weff<true>), dim3((DIM_ * F_) / 256), dim3(256), 0, stream,
                       proj_w, conv_w, alpha, (void*)Wt);
    hipLaunchKernelGGL((k_tab<true, true>), dim3(9 * V_), dim3(256), 0, stream,
                       emb, (const void*)Wt, (void*)T);
    hipLaunchKernelGGL((k_main<true>), dim3(NROWS / 4), dim3(256), 0, stream,
                       x, (const void*)T, beff, gamma, beta, out);
  } else {
    // D: tiny ws (needs 518,144 B). No T table: init + 9 accumulate passes + LN.
    unsigned short* Wt = (unsigned short*)(wsbase + 2048);
    hipLaunchKernelGGL((k_weff<true>), dim3((DIM_ * F_) / 256), dim3(256), 0, stream,
                       proj_w, conv_w, alpha, (void*)Wt);
    hipLaunchKernelGGL(k_init, dim3((NROWS * DIM_ / 4) / 256), dim3(256), 0, stream,
                       beff, out);
    for (int q = 0; q < 9; ++q)
      hipLaunchKernelGGL(k_accq, dim3(128, 2), dim3(256), 0, stream,
                         x, emb, Wt, out, q);
    hipLaunchKernelGGL(k_ln, dim3(NROWS / 4), dim3(256), 0, stream,
                       gamma, beta, out);
  }
}

// Round 4
// 157.311 us; speedup vs baseline: 1.1981x; 1.1981x over previous
//
#include <hip/hip_runtime.h>

#define E_ 56
#define DIM_ 512
#define V_ 256
#define F_ 504       // E_*9
#define NROWS 65536  // B*L

typedef float  vf4 __attribute__((ext_vector_type(4)));

__device__ __forceinline__ float sigmoidf_(float v) { return 1.0f / (1.0f + expf(-v)); }
__device__ __forceinline__ float bf_lo_(unsigned int u) {
  return __uint_as_float(u << 16);
}
__device__ __forceinline__ float bf_hi_(unsigned int u) {
  return __uint_as_float(u & 0xFFFF0000u);
}
__device__ __forceinline__ float bf2f_(unsigned short u) {
  return __uint_as_float(((unsigned int)u) << 16);
}
__device__ __forceinline__ unsigned short f2bf_(float f) {  // round-nearest-even
  unsigned int b = __float_as_uint(f);
  b += 0x7FFFu + ((b >> 16) & 1u);
  return (unsigned short)(b >> 16);
}

// ---------------- Weff fold: conv + gate + projection -> one linear map ----
// Wt layout: [q][c][d], d contiguous. BF selects bf16 vs f32 storage.
template<bool BF>
__global__ __launch_bounds__(256) void k_weff(
    const float* __restrict__ proj_w,   // [512][504]
    const float* __restrict__ conv_w,   // [56][56][3][3]
    const float* __restrict__ alpha,    // [9]
    void* __restrict__ Wt)
{
  int idx = blockIdx.x * 256 + threadIdx.x;   // 512*504 threads
  int d = idx / F_;
  int f = idx - d * F_;
  int c = f / 9;
  int q = f - c * 9;
  int qi = q / 3, qj = q - qi * 3;
  const float* pr = proj_w + d * F_;
  float acc = sigmoidf_(alpha[q]) * pr[c * 9 + q];
  for (int pi = 0; pi < 3; ++pi) {
    for (int pj = 0; pj < 3; ++pj) {
      int ki = qi - pi + 1, kj = qj - pj + 1;
      if (ki < 0 || ki > 2 || kj < 0 || kj > 2) continue;
      int p = pi * 3 + pj;
      const float* cwp = conv_w + c * 9 + (ki * 3 + kj);
      const float* prp = pr + p;
      float s = 0.f;
      #pragma unroll 8
      for (int e = 0; e < E_; ++e)
        s += prp[e * 9] * cwp[e * F_];
      acc += (1.f - sigmoidf_(alpha[p])) * s;
    }
  }
  size_t o = (size_t)(q * E_ + c) * DIM_ + d;
  if (BF) ((unsigned short*)Wt)[o] = f2bf_(acc);
  else    ((float*)Wt)[o] = acc;
}

__global__ __launch_bounds__(256) void k_beff(
    const float* __restrict__ proj_w,
    const float* __restrict__ conv_b,
    const float* __restrict__ proj_b,
    const float* __restrict__ alpha,
    float* __restrict__ beff)           // [512]
{
  int d = blockIdx.x * 256 + threadIdx.x;
  if (d >= DIM_) return;
  const float* pr = proj_w + d * F_;
  float acc = proj_b[d];
  for (int p = 0; p < 9; ++p) {
    float s = 0.f;
    for (int e = 0; e < E_; ++e) s += pr[e * 9 + p] * conv_b[e];
    acc += (1.f - sigmoidf_(alpha[p])) * s;
  }
  beff[d] = acc;
}

// T[q][t][d] = sum_c emb[t][c] * Wt[q][c][d];  Wt f32, T bf16.
__global__ __launch_bounds__(256) void k_tab(
    const float* __restrict__ emb,      // [256][56]
    const float* __restrict__ Wt,       // [9][56][512] f32
    unsigned short* __restrict__ T)     // [9][256][512] bf16
{
  int q = blockIdx.x >> 8;
  int t = blockIdx.x & 255;
  int d0 = 2 * threadIdx.x;
  const float* er = emb + t * E_;
  float a0 = 0.f, a1 = 0.f;
  for (int c = 0; c < E_; ++c) {
    float ev = er[c];
    float2 v = *(const float2*)(Wt + (size_t)(q * E_ + c) * DIM_ + d0);
    a0 += ev * v.x; a1 += ev * v.y;
  }
  size_t o = (size_t)(q * V_ + t) * DIM_ + d0;
  unsigned int u = (unsigned int)f2bf_(a0) | ((unsigned int)f2bf_(a1) << 16);
  *(unsigned int*)(T + o) = u;
}

// Shared LayerNorm tail helpers ------------------------------------------------
__device__ __forceinline__ void ln_reduce_(const float a[8], float& mu, float& rstd) {
  float s = 0.f, ss = 0.f;
  #pragma unroll
  for (int j = 0; j < 8; ++j) { s += a[j]; ss += a[j] * a[j]; }
  #pragma unroll
  for (int off = 32; off > 0; off >>= 1) {
    s  += __shfl_xor(s, off, 64);
    ss += __shfl_xor(ss, off, 64);
  }
  mu = s * (1.0f / 512.0f);
  float var = ss * (1.0f / 512.0f) - mu * mu;
  rstd = rsqrtf(var + 1e-5f);
}

// One wave per row: 9 bf16 table gathers (one uint4 = 8 bf16 per q) + LN.
// d = lane*8 + j.
__global__ __launch_bounds__(256) void k_main_bf(
    const int*            __restrict__ x,     // [65536][9]
    const unsigned short* __restrict__ T,     // [9][256][512] bf16
    const float* __restrict__ beff,
    const float* __restrict__ gamma,
    const float* __restrict__ beta,
    float* __restrict__ out)                  // [65536][512]
{
  int gid = blockIdx.x * 256 + threadIdx.x;
  int row = gid >> 6;
  int lane = threadIdx.x & 63;
  int tok = 0;
  if (lane < 9) tok = x[row * 9 + lane];

  const float4* b4 = (const float4*)beff;
  float4 B0 = b4[2 * lane], B1 = b4[2 * lane + 1];
  float a[8] = {B0.x, B0.y, B0.z, B0.w, B1.x, B1.y, B1.z, B1.w};

  #pragma unroll
  for (int q = 0; q < 9; ++q) {
    int t = __shfl(tok, q, 64);
    const uint4* p = (const uint4*)(T + (size_t)((q << 8) + t) * DIM_) + lane;
    uint4 u = *p;
    a[0] += bf_lo_(u.x); a[1] += bf_hi_(u.x);
    a[2] += bf_lo_(u.y); a[3] += bf_hi_(u.y);
    a[4] += bf_lo_(u.z); a[5] += bf_hi_(u.z);
    a[6] += bf_lo_(u.w); a[7] += bf_hi_(u.w);
  }

  float mu, rstd;
  ln_reduce_(a, mu, rstd);

  const float4* g4  = (const float4*)gamma;
  const float4* be4 = (const float4*)beta;
  float4 G0 = g4[2 * lane], G1 = g4[2 * lane + 1];
  float4 P0 = be4[2 * lane], P1 = be4[2 * lane + 1];

  vf4 o0, o1;
  o0.x = (a[0] - mu) * rstd * G0.x + P0.x;
  o0.y = (a[1] - mu) * rstd * G0.y + P0.y;
  o0.z = (a[2] - mu) * rstd * G0.z + P0.z;
  o0.w = (a[3] - mu) * rstd * G0.w + P0.w;
  o1.x = (a[4] - mu) * rstd * G1.x + P1.x;
  o1.y = (a[5] - mu) * rstd * G1.y + P1.y;
  o1.z = (a[6] - mu) * rstd * G1.z + P1.z;
  o1.w = (a[7] - mu) * rstd * G1.w + P1.w;

  vf4* o4 = (vf4*)(out + (size_t)row * DIM_ + lane * 8);
  __builtin_nontemporal_store(o0, o4);
  __builtin_nontemporal_store(o1, o4 + 1);
}

// ----------------- D bracket (tiny ws): no T table -------------------------
__global__ __launch_bounds__(256) void k_init(
    const float* __restrict__ beff, float* __restrict__ out)
{
  int idx = blockIdx.x * 256 + threadIdx.x;     // 8,388,608 float4s
  ((float4*)out)[idx] = ((const float4*)beff)[idx & 127];
}

__global__ __launch_bounds__(256) void k_accq(
    const int* __restrict__ x,
    const float* __restrict__ emb,
    const unsigned short* __restrict__ Wt,      // bf16 [9][56][512]
    float* __restrict__ out, int q)
{
  const int tid = threadIdx.x;
  const int d = blockIdx.y * 256 + tid;
  const int row0 = blockIdx.x * 512;
  const unsigned short* wq = Wt + (size_t)(q * E_) * DIM_ + d;

  for (int rb = 0; rb < 512; rb += 8) {
    int tv[8]; float a[8];
    #pragma unroll
    for (int j = 0; j < 8; ++j) {
      tv[j] = x[(size_t)(row0 + rb + j) * 9 + q];
      a[j] = 0.f;
    }
    for (int c = 0; c < E_; ++c) {
      float w = bf2f_(wq[(size_t)c * DIM_]);
      #pragma unroll
      for (int j = 0; j < 8; ++j)
        a[j] += emb[tv[j] * E_ + c] * w;
    }
    #pragma unroll
    for (int j = 0; j < 8; ++j) {
      size_t o = (size_t)(row0 + rb + j) * DIM_ + d;
      out[o] += a[j];
    }
  }
}

__global__ __launch_bounds__(256) void k_ln(
    const float* __restrict__ gamma, const float* __restrict__ beta,
    float* __restrict__ out)
{
  int gid = blockIdx.x * 256 + threadIdx.x;
  int row = gid >> 6;
  int lane = threadIdx.x & 63;
  float* op = out + (size_t)row * DIM_ + lane * 8;
  float4 A0 = *(float4*)op, A1 = *(float4*)(op + 4);
  float a[8] = {A0.x, A0.y, A0.z, A0.w, A1.x, A1.y, A1.z, A1.w};
  float mu, rstd;
  ln_reduce_(a, mu, rstd);
  const float4* g4  = (const float4*)gamma;
  const float4* be4 = (const float4*)beta;
  float4 G0 = g4[2 * lane], G1 = g4[2 * lane + 1];
  float4 P0 = be4[2 * lane], P1 = be4[2 * lane + 1];
  float4 o0, o1;
  o0.x = (a[0] - mu) * rstd * G0.x + P0.x;
  o0.y = (a[1] - mu) * rstd * G0.y + P0.y;
  o0.z = (a[2] - mu) * rstd * G0.z + P0.z;
  o0.w = (a[3] - mu) * rstd * G0.w + P0.w;
  o1.x = (a[4] - mu) * rstd * G1.x + P1.x;
  o1.y = (a[5] - mu) * rstd * G1.y + P1.y;
  o1.z = (a[6] - mu) * rstd * G1.z + P1.z;
  o1.w = (a[7] - mu) * rstd * G1.w + P1.w;
  *(float4*)op = o0;
  *(float4*)(op + 4) = o1;
}

extern "C" void kernel_launch(void* const* d_in, const int* in_sizes, int n_in,
                              void* d_out, int out_size, void* d_ws, size_t ws_size,
                              hipStream_t stream) {
  const int*   x      = (const int*)  d_in[0];
  const float* emb    = (const float*)d_in[1];
  const float* alpha  = (const float*)d_in[2];
  const float* conv_w = (const float*)d_in[3];
  const float* conv_b = (const float*)d_in[4];
  const float* proj_w = (const float*)d_in[5];
  const float* proj_b = (const float*)d_in[6];
  const float* gamma  = (const float*)d_in[7];
  const float* beta   = (const float*)d_in[8];
  float* out = (float*)d_out;

  float* beff = (float*)d_ws;
  char* wsbase = (char*)d_ws;

  const size_t WT_F32 = (size_t)9 * E_ * DIM_ * 4;   // 1,032,192
  const size_t T_BF   = (size_t)9 * V_ * DIM_ * 2;   // 2,359,296
  const size_t needMain = 2048 + WT_F32 + T_BF;      // 3,393,536

  hipLaunchKernelGGL(k_beff, dim3(2), dim3(256), 0, stream,
                     proj_w, conv_b, proj_b, alpha, beff);

  if (ws_size >= needMain) {
    // Primary: Wt f32 (precision) + T bf16 (L2-resident, 2.36 MB/XCD).
    float* Wt = (float*)(wsbase + 2048);
    unsigned short* T = (unsigned short*)(wsbase + 2048 + WT_F32);
    hipLaunchKernelGGL((k_weff<false>), dim3((DIM_ * F_) / 256), dim3(256), 0, stream,
                       proj_w, conv_w, alpha, (void*)Wt);
    hipLaunchKernelGGL(k_tab, dim3(9 * V_), dim3(256), 0, stream,
                       emb, Wt, T);
    hipLaunchKernelGGL(k_main_bf, dim3(NROWS / 4), dim3(256), 0, stream,
                       x, T, beff, gamma, beta, out);
  } else {
    // Fallback: tiny ws (needs 518,144 B). init + 9 accumulate passes + LN.
    unsigned short* Wt = (unsigned short*)(wsbase + 2048);
    hipLaunchKernelGGL((k_weff<true>), dim3((DIM_ * F_) / 256), dim3(256), 0, stream,
                       proj_w, conv_w, alpha, (void*)Wt);
    hipLaunchKernelGGL(k_init, dim3((NROWS * DIM_ / 4) / 256), dim3(256), 0, stream,
                       beff, out);
    for (int q = 0; q < 9; ++q)
      hipLaunchKernelGGL(k_accq, dim3(128, 2), dim3(256), 0, stream,
                         x, emb, Wt, out, q);
    hipLaunchKernelGGL(k_ln, dim3(NROWS / 4), dim3(256), 0, stream,
                       gamma, beta, out);
  }
}